// Round 1
// baseline (89.865 us; speedup 1.0000x reference)
//
#include <hip/hip_runtime.h>
#include <math.h>

#define B 32
#define N 2048
#define EPS 1e-6f
#define TILE 256            // query points (threads) per block
#define NTILES (N / TILE)   // 8

__global__ __launch_bounds__(256) void chamfer_min_kernel(
    const float* __restrict__ pred, const float* __restrict__ target,
    float* __restrict__ partial) {
  const int b = blockIdx.y;
  const int t = blockIdx.x;        // 0..15
  const int dir = t / NTILES;      // 0: pred->target, 1: target->pred
  const int tile = t % NTILES;

  const float* qbase = (dir == 0) ? pred : target;
  const float* rbase = (dir == 0) ? target : pred;

  __shared__ float2 refs[N];       // 16 KB
  // cooperative staging: N*2 floats = 1024 float4; 256 threads x 4 each
  const float4* rsrc = (const float4*)(rbase + (size_t)b * N * 2);
  float4* rdst = (float4*)refs;
#pragma unroll
  for (int k = 0; k < (N * 2 / 4) / TILE; ++k) {
    rdst[k * TILE + threadIdx.x] = rsrc[k * TILE + threadIdx.x];
  }
  __syncthreads();

  const int qi = tile * TILE + threadIdx.x;
  const float2 q = ((const float2*)(qbase + (size_t)b * N * 2))[qi];

  float m = 3.4e38f;
  const float4* rs4 = (const float4*)refs;
#pragma unroll 8
  for (int j = 0; j < N / 2; ++j) {
    float4 r = rs4[j];                       // 2 ref points, LDS broadcast
    float dx0 = q.x - r.x, dy0 = q.y - r.y;
    float dx1 = q.x - r.z, dy1 = q.y - r.w;
    float d0 = fmaf(dy0, dy0, dx0 * dx0);
    float d1 = fmaf(dy1, dy1, dx1 * dx1);
    m = fminf(m, fminf(d0, d1));             // v_min3 candidate
  }
  float v = sqrtf(m + EPS);

  // deterministic block reduction
#pragma unroll
  for (int off = 32; off > 0; off >>= 1)
    v += __shfl_down(v, off, 64);
  __shared__ float wsum[4];
  const int wid = threadIdx.x >> 6;
  if ((threadIdx.x & 63) == 0) wsum[wid] = v;
  __syncthreads();
  if (threadIdx.x == 0) {
    float s = wsum[0] + wsum[1] + wsum[2] + wsum[3];
    partial[blockIdx.y * 16 + blockIdx.x] = s;
  }
}

__global__ __launch_bounds__(512) void chamfer_reduce_kernel(
    const float* __restrict__ partial, float* __restrict__ out) {
  // 512 partials, 1 block of 512 threads; fully deterministic tree
  float v = partial[threadIdx.x];
#pragma unroll
  for (int off = 32; off > 0; off >>= 1)
    v += __shfl_down(v, off, 64);
  __shared__ float wsum[8];
  const int wid = threadIdx.x >> 6;
  if ((threadIdx.x & 63) == 0) wsum[wid] = v;
  __syncthreads();
  if (threadIdx.x == 0) {
    float s = 0.f;
#pragma unroll
    for (int i = 0; i < 8; ++i) s += wsum[i];
    out[0] = s * (1.0f / (float)(B * N));   // LOSS_WEIGHT = 1
  }
}

extern "C" void kernel_launch(void* const* d_in, const int* in_sizes, int n_in,
                              void* d_out, int out_size, void* d_ws, size_t ws_size,
                              hipStream_t stream) {
  const float* pred   = (const float*)d_in[0];
  const float* target = (const float*)d_in[1];
  float* out     = (float*)d_out;
  float* partial = (float*)d_ws;   // 512 floats = 2 KB

  dim3 grid(2 * NTILES, B);        // (16, 32) = 512 blocks
  chamfer_min_kernel<<<grid, TILE, 0, stream>>>(pred, target, partial);
  chamfer_reduce_kernel<<<1, 512, 0, stream>>>(partial, out);
}

// Round 2
// 32.799 us; speedup vs baseline: 2.7398x; 2.7398x over previous
//
#include <hip/hip_runtime.h>
#include <math.h>

#define B 32
#define N 2048
#define EPS 1e-6f
#define TILE 256              // query points (threads) per block
#define CHUNK 512             // ref points per block
#define NCHUNK (N / CHUNK)    // 4
#define NTILES (N / TILE)     // 8
#define NQ_TOTAL (2 * B * N)  // 131072 query slots (both directions)

// Stage 1: partial min of squared distances over one 512-ref chunk.
__global__ __launch_bounds__(256) void chamfer_min_kernel(
    const float* __restrict__ pred, const float* __restrict__ target,
    float* __restrict__ pmin) {
  const int tile = blockIdx.x;   // 0..7
  const int c    = blockIdx.y;   // 0..3 ref chunk
  const int db   = blockIdx.z;   // 0..63 : dir*32 + b
  const int dir  = db >> 5;
  const int b    = db & 31;

  const float* qbase = (dir == 0) ? pred : target;
  const float* rbase = (dir == 0) ? target : pred;

  __shared__ float2 refs[CHUNK];   // 4 KB
  // stage 512 refs = 256 float4, one per thread
  const float4* rsrc = (const float4*)(rbase + (size_t)b * N * 2);
  ((float4*)refs)[threadIdx.x] = rsrc[c * (CHUNK / 2) + threadIdx.x];
  __syncthreads();

  const int qi = tile * TILE + threadIdx.x;
  const float2 q = ((const float2*)(qbase + (size_t)b * N * 2))[qi];

  // two independent min chains to break the 4-cyc fmin dependency
  float m0 = 3.4e38f, m1 = 3.4e38f;
  const float4* rs4 = (const float4*)refs;
#pragma unroll 8
  for (int j = 0; j < CHUNK / 4; ++j) {
    float4 r0 = rs4[2 * j];
    float4 r1 = rs4[2 * j + 1];
    float dx0 = q.x - r0.x, dy0 = q.y - r0.y;
    float dx1 = q.x - r0.z, dy1 = q.y - r0.w;
    float dx2 = q.x - r1.x, dy2 = q.y - r1.y;
    float dx3 = q.x - r1.z, dy3 = q.y - r1.w;
    float d0 = fmaf(dy0, dy0, dx0 * dx0);
    float d1 = fmaf(dy1, dy1, dx1 * dx1);
    float d2 = fmaf(dy2, dy2, dx2 * dx2);
    float d3 = fmaf(dy3, dy3, dx3 * dx3);
    m0 = fminf(fminf(m0, d0), d1);   // v_min3
    m1 = fminf(fminf(m1, d2), d3);   // v_min3
  }
  float m = fminf(m0, m1);

  // pmin[(db*NCHUNK + c)*N + qi]
  pmin[((size_t)db * NCHUNK + c) * N + qi] = m;
}

// Stage 2: per-query min over chunks, sqrt, block-sum.
__global__ __launch_bounds__(256) void chamfer_combine_kernel(
    const float* __restrict__ pmin, float* __restrict__ partial2) {
  const int idx = blockIdx.x * 256 + threadIdx.x;  // 0..32767
  float s = 0.f;
#pragma unroll
  for (int k = 0; k < 4; ++k) {
    const int g  = k * 32768 + idx;       // 0..131071
    const int db = g >> 11;               // /2048
    const int qi = g & 2047;
    const float* p = pmin + ((size_t)db * NCHUNK) * N + qi;
    float v = fminf(fminf(p[0], p[N]), fminf(p[2 * N], p[3 * N]));
    s += sqrtf(v + EPS);
  }
#pragma unroll
  for (int off = 32; off > 0; off >>= 1)
    s += __shfl_down(s, off, 64);
  __shared__ float wsum[4];
  const int wid = threadIdx.x >> 6;
  if ((threadIdx.x & 63) == 0) wsum[wid] = s;
  __syncthreads();
  if (threadIdx.x == 0)
    partial2[blockIdx.x] = wsum[0] + wsum[1] + wsum[2] + wsum[3];
}

// Stage 3: final 128-way reduce, scale, write scalar.
__global__ __launch_bounds__(128) void chamfer_final_kernel(
    const float* __restrict__ partial2, float* __restrict__ out) {
  float v = partial2[threadIdx.x];
#pragma unroll
  for (int off = 32; off > 0; off >>= 1)
    v += __shfl_down(v, off, 64);
  __shared__ float wsum[2];
  if ((threadIdx.x & 63) == 0) wsum[threadIdx.x >> 6] = v;
  __syncthreads();
  if (threadIdx.x == 0)
    out[0] = (wsum[0] + wsum[1]) * (1.0f / (float)(B * N));
}

extern "C" void kernel_launch(void* const* d_in, const int* in_sizes, int n_in,
                              void* d_out, int out_size, void* d_ws, size_t ws_size,
                              hipStream_t stream) {
  const float* pred   = (const float*)d_in[0];
  const float* target = (const float*)d_in[1];
  float* out = (float*)d_out;

  float* pmin     = (float*)d_ws;                       // 2*32*4*2048 = 524288 floats (2 MB)
  float* partial2 = (float*)d_ws + (size_t)2 * B * NCHUNK * N;  // 128 floats

  dim3 grid1(NTILES, NCHUNK, 2 * B);   // (8,4,64) = 2048 blocks
  chamfer_min_kernel<<<grid1, TILE, 0, stream>>>(pred, target, pmin);
  chamfer_combine_kernel<<<NQ_TOTAL / 4 / 256, 256, 0, stream>>>(pmin, partial2);
  chamfer_final_kernel<<<1, 128, 0, stream>>>(partial2, out);
}

// Round 3
// 31.914 us; speedup vs baseline: 2.8159x; 1.0277x over previous
//
#include <hip/hip_runtime.h>
#include <math.h>
#include <float.h>

#define B 32
#define N 2048
#define EPS 1e-6f
#define TILE 256              // query points (threads) per block
#define CHUNK 512             // ref points per block
#define NCHUNK (N / CHUNK)    // 4
#define NTILES (N / TILE)     // 8
#define NQ_TOTAL (2 * B * N)  // 131072 query slots (both directions)

// Stage 1: partial min over one 512-ref chunk of t = |r|^2 - 2 q.r  (+|q|^2 at end).
__global__ __launch_bounds__(256) void chamfer_min_kernel(
    const float* __restrict__ pred, const float* __restrict__ target,
    float* __restrict__ pmin) {
  const int tile = blockIdx.x;   // 0..7
  const int c    = blockIdx.y;   // 0..3 ref chunk
  const int db   = blockIdx.z;   // 0..63 : dir*32 + b
  const int dir  = db >> 5;
  const int b    = db & 31;

  const float* qbase = (dir == 0) ? pred : target;
  const float* rbase = (dir == 0) ? target : pred;

  // SoA-by-4 layout: group g of 4 refs -> L[3g]=(-2x)x4, L[3g+1]=(-2y)x4, L[3g+2]=(|r|^2)x4
  __shared__ float4 L[3 * CHUNK / 4];   // 6 KB

  {
    const float4* rsrc = (const float4*)(rbase + (size_t)b * N * 2);
    float4 rv = rsrc[c * (CHUNK / 2) + threadIdx.x];  // refs 2t, 2t+1
    float rx2a = -2.f * rv.x, ry2a = -2.f * rv.y;
    float rx2b = -2.f * rv.z, ry2b = -2.f * rv.w;
    float cra  = fmaf(rv.x, rv.x, rv.y * rv.y);
    float crb  = fmaf(rv.z, rv.z, rv.w * rv.w);
    float* Lf = (float*)L;
    const int base = 12 * (threadIdx.x >> 1) + 2 * (threadIdx.x & 1);
    *(float2*)(Lf + base + 0) = make_float2(rx2a, rx2b);
    *(float2*)(Lf + base + 4) = make_float2(ry2a, ry2b);
    *(float2*)(Lf + base + 8) = make_float2(cra,  crb);
  }
  __syncthreads();

  const int qi = tile * TILE + threadIdx.x;
  const float2 q = ((const float2*)(qbase + (size_t)b * N * 2))[qi];

  float m0 = FLT_MAX, m1 = FLT_MAX;
#pragma unroll 4
  for (int jj = 0; jj < CHUNK / 4; ++jj) {
    float4 X = L[3 * jj];
    float4 Y = L[3 * jj + 1];
    float4 C = L[3 * jj + 2];
    float d0 = fmaf(X.x, q.x, fmaf(Y.x, q.y, C.x));
    float d1 = fmaf(X.y, q.x, fmaf(Y.y, q.y, C.y));
    float d2 = fmaf(X.z, q.x, fmaf(Y.z, q.y, C.z));
    float d3 = fmaf(X.w, q.x, fmaf(Y.w, q.y, C.w));
    m0 = fminf(fminf(m0, d0), d1);   // v_min3
    m1 = fminf(fminf(m1, d2), d3);   // v_min3
  }
  const float qq = fmaf(q.x, q.x, q.y * q.y);
  pmin[((size_t)db * NCHUNK + c) * N + qi] = fminf(m0, m1) + qq;
}

// Stage 2: per-query min over 4 chunks, sqrt, block-sum. 1 slot/thread.
__global__ __launch_bounds__(256) void chamfer_combine_kernel(
    const float* __restrict__ pmin, float* __restrict__ partial2) {
  const int g  = blockIdx.x * 256 + threadIdx.x;  // 0..131071
  const int db = g >> 11;
  const int qi = g & 2047;
  const float* p = pmin + (size_t)db * NCHUNK * N + qi;
  float v = fminf(fminf(p[0], p[N]), fminf(p[2 * N], p[3 * N]));
  float s = sqrtf(fmaxf(v, 0.f) + EPS);
#pragma unroll
  for (int off = 32; off > 0; off >>= 1)
    s += __shfl_down(s, off, 64);
  __shared__ float wsum[4];
  const int wid = threadIdx.x >> 6;
  if ((threadIdx.x & 63) == 0) wsum[wid] = s;
  __syncthreads();
  if (threadIdx.x == 0)
    partial2[blockIdx.x] = wsum[0] + wsum[1] + wsum[2] + wsum[3];
}

// Stage 3: final 512-way reduce, scale, write scalar.
__global__ __launch_bounds__(512) void chamfer_final_kernel(
    const float* __restrict__ partial2, float* __restrict__ out) {
  float v = partial2[threadIdx.x];
#pragma unroll
  for (int off = 32; off > 0; off >>= 1)
    v += __shfl_down(v, off, 64);
  __shared__ float wsum[8];
  if ((threadIdx.x & 63) == 0) wsum[threadIdx.x >> 6] = v;
  __syncthreads();
  if (threadIdx.x == 0) {
    float s = 0.f;
#pragma unroll
    for (int i = 0; i < 8; ++i) s += wsum[i];
    out[0] = s * (1.0f / (float)(B * N));
  }
}

extern "C" void kernel_launch(void* const* d_in, const int* in_sizes, int n_in,
                              void* d_out, int out_size, void* d_ws, size_t ws_size,
                              hipStream_t stream) {
  const float* pred   = (const float*)d_in[0];
  const float* target = (const float*)d_in[1];
  float* out = (float*)d_out;

  float* pmin     = (float*)d_ws;                                 // 524288 floats (2 MB)
  float* partial2 = (float*)d_ws + (size_t)2 * B * NCHUNK * N;    // 512 floats

  dim3 grid1(NTILES, NCHUNK, 2 * B);   // (8,4,64) = 2048 blocks
  chamfer_min_kernel<<<grid1, TILE, 0, stream>>>(pred, target, pmin);
  chamfer_combine_kernel<<<NQ_TOTAL / 256, 256, 0, stream>>>(pmin, partial2);
  chamfer_final_kernel<<<1, 512, 0, stream>>>(partial2, out);
}

// Round 4
// 25.760 us; speedup vs baseline: 3.4885x; 1.2389x over previous
//
#include <hip/hip_runtime.h>
#include <math.h>
#include <float.h>

#define B 32
#define N 2048
#define EPS 1e-6f
#define TILE 128              // threads per block
#define Q 2                   // queries per thread
#define QBLK (TILE * Q)       // 256 queries per block
#define CHUNK 512             // ref points per block
#define NCHUNK (N / CHUNK)    // 4
#define NTILES (N / QBLK)     // 8
#define NQ_TOTAL (2 * B * N)  // 131072 query slots (both directions)

// Stage 1: partial min over one 512-ref chunk of t = |r|^2 - 2 q.r  (+|q|^2 at end).
// Q=2 queries per thread amortizes each LDS broadcast read over 2 query points.
__global__ __launch_bounds__(128) void chamfer_min_kernel(
    const float* __restrict__ pred, const float* __restrict__ target,
    float* __restrict__ pmin) {
  const int tile = blockIdx.x;   // 0..7
  const int c    = blockIdx.y;   // 0..3 ref chunk
  const int db   = blockIdx.z;   // 0..63 : dir*32 + b
  const int dir  = db >> 5;
  const int b    = db & 31;

  const float* qbase = (dir == 0) ? pred : target;
  const float* rbase = (dir == 0) ? target : pred;

  // SoA-by-4: group g of 4 refs -> L[3g]=(-2x)x4, L[3g+1]=(-2y)x4, L[3g+2]=(|r|^2)x4
  __shared__ float4 L[3 * CHUNK / 4];   // 6 KB

  {
    // 512 refs = 256 float4; 128 threads load 2 each
    const float4* rsrc = (const float4*)(rbase + (size_t)b * N * 2) + c * (CHUNK / 2);
    float* Lf = (float*)L;
#pragma unroll
    for (int k = 0; k < 2; ++k) {
      const int t = threadIdx.x + k * TILE;       // virtual thread 0..255
      float4 rv = rsrc[t];                         // refs 2t, 2t+1
      float rx2a = -2.f * rv.x, ry2a = -2.f * rv.y;
      float rx2b = -2.f * rv.z, ry2b = -2.f * rv.w;
      float cra  = fmaf(rv.x, rv.x, rv.y * rv.y);
      float crb  = fmaf(rv.z, rv.z, rv.w * rv.w);
      const int base = 12 * (t >> 1) + 2 * (t & 1);
      *(float2*)(Lf + base + 0) = make_float2(rx2a, rx2b);
      *(float2*)(Lf + base + 4) = make_float2(ry2a, ry2b);
      *(float2*)(Lf + base + 8) = make_float2(cra,  crb);
    }
  }
  __syncthreads();

  // this thread's Q queries: qi_k = tile*QBLK + threadIdx.x + k*TILE (coalesced)
  const float2* qsrc = (const float2*)(qbase + (size_t)b * N * 2) + tile * QBLK;
  float2 q0 = qsrc[threadIdx.x];
  float2 q1 = qsrc[threadIdx.x + TILE];

  float a00 = FLT_MAX, a01 = FLT_MAX;   // two chains for q0
  float a10 = FLT_MAX, a11 = FLT_MAX;   // two chains for q1
#pragma unroll 4
  for (int jj = 0; jj < CHUNK / 4; ++jj) {
    float4 X = L[3 * jj];
    float4 Y = L[3 * jj + 1];
    float4 C = L[3 * jj + 2];
    // q0
    float d0 = fmaf(X.x, q0.x, fmaf(Y.x, q0.y, C.x));
    float d1 = fmaf(X.y, q0.x, fmaf(Y.y, q0.y, C.y));
    float d2 = fmaf(X.z, q0.x, fmaf(Y.z, q0.y, C.z));
    float d3 = fmaf(X.w, q0.x, fmaf(Y.w, q0.y, C.w));
    a00 = fminf(fminf(a00, d0), d1);
    a01 = fminf(fminf(a01, d2), d3);
    // q1
    float e0 = fmaf(X.x, q1.x, fmaf(Y.x, q1.y, C.x));
    float e1 = fmaf(X.y, q1.x, fmaf(Y.y, q1.y, C.y));
    float e2 = fmaf(X.z, q1.x, fmaf(Y.z, q1.y, C.z));
    float e3 = fmaf(X.w, q1.x, fmaf(Y.w, q1.y, C.w));
    a10 = fminf(fminf(a10, e0), e1);
    a11 = fminf(fminf(a11, e2), e3);
  }
  const float qq0 = fmaf(q0.x, q0.x, q0.y * q0.y);
  const float qq1 = fmaf(q1.x, q1.x, q1.y * q1.y);

  float* dst = pmin + ((size_t)db * NCHUNK + c) * N + tile * QBLK;
  dst[threadIdx.x]        = fminf(a00, a01) + qq0;
  dst[threadIdx.x + TILE] = fminf(a10, a11) + qq1;
}

// Stage 2: per-query min over 4 chunks, sqrt, block-sum. 1 slot/thread.
__global__ __launch_bounds__(256) void chamfer_combine_kernel(
    const float* __restrict__ pmin, float* __restrict__ partial2) {
  const int g  = blockIdx.x * 256 + threadIdx.x;  // 0..131071
  const int db = g >> 11;
  const int qi = g & 2047;
  const float* p = pmin + (size_t)db * NCHUNK * N + qi;
  float v = fminf(fminf(p[0], p[N]), fminf(p[2 * N], p[3 * N]));
  float s = sqrtf(fmaxf(v, 0.f) + EPS);
#pragma unroll
  for (int off = 32; off > 0; off >>= 1)
    s += __shfl_down(s, off, 64);
  __shared__ float wsum[4];
  const int wid = threadIdx.x >> 6;
  if ((threadIdx.x & 63) == 0) wsum[wid] = s;
  __syncthreads();
  if (threadIdx.x == 0)
    partial2[blockIdx.x] = wsum[0] + wsum[1] + wsum[2] + wsum[3];
}

// Stage 3: final 512-way reduce, scale, write scalar.
__global__ __launch_bounds__(512) void chamfer_final_kernel(
    const float* __restrict__ partial2, float* __restrict__ out) {
  float v = partial2[threadIdx.x];
#pragma unroll
  for (int off = 32; off > 0; off >>= 1)
    v += __shfl_down(v, off, 64);
  __shared__ float wsum[8];
  if ((threadIdx.x & 63) == 0) wsum[threadIdx.x >> 6] = v;
  __syncthreads();
  if (threadIdx.x == 0) {
    float s = 0.f;
#pragma unroll
    for (int i = 0; i < 8; ++i) s += wsum[i];
    out[0] = s * (1.0f / (float)(B * N));
  }
}

extern "C" void kernel_launch(void* const* d_in, const int* in_sizes, int n_in,
                              void* d_out, int out_size, void* d_ws, size_t ws_size,
                              hipStream_t stream) {
  const float* pred   = (const float*)d_in[0];
  const float* target = (const float*)d_in[1];
  float* out = (float*)d_out;

  float* pmin     = (float*)d_ws;                                 // 524288 floats (2 MB)
  float* partial2 = (float*)d_ws + (size_t)2 * B * NCHUNK * N;    // 512 floats

  dim3 grid1(NTILES, NCHUNK, 2 * B);   // (8,4,64) = 2048 blocks
  chamfer_min_kernel<<<grid1, TILE, 0, stream>>>(pred, target, pmin);
  chamfer_combine_kernel<<<NQ_TOTAL / 256, 256, 0, stream>>>(pmin, partial2);
  chamfer_final_kernel<<<1, 512, 0, stream>>>(partial2, out);
}